// Round 10
// baseline (474.478 us; speedup 1.0000x reference)
//
#include <hip/hip_runtime.h>

// RallyNet latent-SDE, round 10.
// k_gru: r7 structure at 512 blocks x 8 batch rows -> 2 blocks/CU (VGPR 76,
//        LDS 28KB both fit): second block fills the barrier-latency gaps.
//        M=16 tiles half-garbage (rows 8-15) - affordable at 6% MfmaUtil.
// k_sde: unchanged r9 (225 us proven): N=32/wave, preP1 ctx-hoist, depth-2
//        prefetch, lgkm-only barriers, in-register Euler-Maruyama.
// diag-g via PWL table (d_ws). ctx[t,b,:] f16 aliases xs_hat[t,b,:] f32.

#define TT 100
#define BB 4096
#define DD 32
#define LL 32
#define CC 64
#define HH 128
#define GROW 260

typedef _Float16 h1;
typedef _Float16 h2 __attribute__((ext_vector_type(2)));
typedef _Float16 f16x8 __attribute__((ext_vector_type(8)));
typedef float f32x4 __attribute__((ext_vector_type(4)));

#define MFMA(a, b, c) __builtin_amdgcn_mfma_f32_16x16x32_f16(a, b, c, 0, 0, 0)
#define PIN(x) asm volatile("" : "+v"(x))

// lgkmcnt-only barrier: orders LDS producer->consumer without draining vmcnt
// (global prefetches/stores stay in flight across phases).
__device__ __forceinline__ void bar_lds() {
  __builtin_amdgcn_sched_barrier(0);
  asm volatile("s_waitcnt lgkmcnt(0)" ::: "memory");
  __builtin_amdgcn_s_barrier();
  asm volatile("" ::: "memory");
  __builtin_amdgcn_sched_barrier(0);
}

__device__ __forceinline__ float sigm(float x) {
  return 1.0f / (1.0f + __expf(-x));
}
__device__ __forceinline__ float tanh_(float x) {
  float e = __expf(2.0f * fminf(x, 15.0f));
  return (e - 1.0f) / (e + 1.0f);
}
__device__ __forceinline__ float splus(float x) {
  return __logf(1.0f + __expf(x));  // inputs bounded |x| << 80
}

// B-fragment of row-major W[N][K] tile (n0,k0)
__device__ __forceinline__ f16x8 bfrag(const float* __restrict__ W, int K,
                                       int n0, int k0, int lane) {
  const float* p = W + (size_t)(n0 + (lane & 15)) * K + k0 + ((lane >> 4) << 3);
  f16x8 r;
#pragma unroll
  for (int j = 0; j < 8; ++j) r[j] = (h1)p[j];
  return r;
}

// A-fragment from LDS row-major tile
__device__ __forceinline__ f16x8 afrag(const h1* base, int ld, int k0,
                                       int lane) {
  return *(const f16x8*)(base + (size_t)(lane & 15) * ld + k0 +
                         ((lane >> 4) << 3));
}

// swizzled f16 weight LDS (rows 256B; XOR bits 4-6 by row&7)
__device__ __forceinline__ void store_swz(h1* base, const float* __restrict__ W,
                                          int rows, int tid, int nthr) {
  for (int idx = tid; idx < rows * 64; idx += nthr) {
    const int n = idx >> 6, kp = idx & 63;
    float2 v = *(const float2*)(W + (size_t)n * HH + 2 * kp);
    h2 hv;
    hv[0] = (h1)v.x;
    hv[1] = (h1)v.y;
    int byte = n * 256 + kp * 4;
    byte ^= (n & 7) << 4;
    *(h2*)((char*)base + byte) = hv;
  }
}
__device__ __forceinline__ f16x8 swzfrag(const h1* base, int n0, int kt,
                                         int lane) {
  const int n = n0 + (lane & 15);
  int byte = n * 256 + kt * 64 + ((lane >> 4) << 4);
  byte ^= (n & 7) << 4;
  return *(const f16x8*)((const char*)base + byte);
}

// ---------------- g-table build ----------------
__global__ __launch_bounds__(320) void k_gtab(
    const float* __restrict__ gW1, const float* __restrict__ gb1,
    const float* __restrict__ gW2, const float* __restrict__ gb2,
    float* __restrict__ gtab) {
  const int l = blockIdx.x;
  const int e = threadIdx.x;
  if (e >= 257) return;
  const float yv = -12.f + (float)e * (24.f / 256.f);
  const float* w1 = gW1 + l * HH;
  const float* bb = gb1 + l * HH;
  const float* w2 = gW2 + l * HH;
  float a = 0.f;
#pragma unroll 4
  for (int h = 0; h < HH; ++h)
    a = fmaf(splus(fmaf(yv, w1[h], bb[h])), w2[h], a);
  gtab[l * GROW + e] = sigm(a + gb2[l]);
}

// ---------------- Kernel 1: GRU + encoder (8 rows/block, 2 blocks/CU) -------
__global__ __launch_bounds__(512, 2) void k_gru(
    const float* __restrict__ xs, const float* __restrict__ Wih,
    const float* __restrict__ Whh, const float* __restrict__ bih,
    const float* __restrict__ bhh, const float* __restrict__ encW,
    const float* __restrict__ encb, h1* __restrict__ ctx16) {
  __shared__ alignas(16) h1 sH[2][16][136];
  __shared__ alignas(16) h1 sX[2][16][40];
  __shared__ alignas(16) h1 sE[64 * 128];  // swizzled encW

  const int tid = threadIdx.x;
  const int lane = tid & 63, w = tid >> 6;
  const int b0 = blockIdx.x * 8;  // 8 batch rows/block
  const int coln = lane & 15, row4 = (lane >> 4) << 2;

  f16x8 wIH[3], wHH[3][4];
#pragma unroll
  for (int g = 0; g < 3; ++g) {
    wIH[g] = bfrag(Wih, DD, 128 * g + 16 * w, 0, lane);
#pragma unroll
    for (int kt = 0; kt < 4; ++kt)
      wHH[g][kt] = bfrag(Whh, HH, 128 * g + 16 * w, 32 * kt, lane);
  }
  const int m = 16 * w + coln;
  const float b_r = bih[m] + bhh[m];
  const float b_z = bih[128 + m] + bhh[128 + m];
  const float b_ni = bih[256 + m];
  const float b_nh = bhh[256 + m];
  const int ccE = (w >= 4) ? 16 * (w - 4) + coln : 0;
  const float bE = (w >= 4) ? encb[ccE] : 0.f;

  store_swz(sE, encW, 64, tid, 512);
  for (int i = tid; i < 16 * 136; i += 512) (&sH[0][0][0])[i] = (h1)0.0f;
  for (int i = tid; i < 2 * 16 * 40; i += 512) (&sX[0][0][0])[i] = (h1)0.0f;
  __syncthreads();
  if (tid < 256) sX[0][tid >> 5][tid & 31] = (h1)xs[(size_t)b0 * DD + tid];
  float xHold =
      (tid < 256) ? xs[(size_t)1 * BB * DD + (size_t)b0 * DD + tid] : 0.f;
  float hold[4] = {0.f, 0.f, 0.f, 0.f};
  __syncthreads();

  for (int t = 0; t < TT; ++t) {
    const int cur = t & 1;
    const int tf = (t + 2 < TT) ? (t + 2) : (TT - 1);
    const float xFly =
        (tid < 256) ? xs[(size_t)tf * BB * DD + (size_t)b0 * DD + tid] : 0.f;

#pragma unroll
    for (int g = 0; g < 3; ++g) {
      PIN(wIH[g]);
#pragma unroll
      for (int kt = 0; kt < 4; ++kt) PIN(wHH[g][kt]);
    }

    f16x8 ax = afrag(&sX[cur][0][0], 40, 0, lane);
    f32x4 aR{b_r, b_r, b_r, b_r}, aZ{b_z, b_z, b_z, b_z};
    f32x4 aNI{b_ni, b_ni, b_ni, b_ni}, aNH{b_nh, b_nh, b_nh, b_nh};
    aR = MFMA(ax, wIH[0], aR);
    aZ = MFMA(ax, wIH[1], aZ);
    aNI = MFMA(ax, wIH[2], aNI);
#pragma unroll
    for (int kt = 0; kt < 4; ++kt) {
      f16x8 ah = afrag(&sH[cur][0][0], 136, 32 * kt, lane);
      aR = MFMA(ah, wHH[0][kt], aR);
      aZ = MFMA(ah, wHH[1][kt], aZ);
      aNH = MFMA(ah, wHH[2][kt], aNH);
    }
#pragma unroll
    for (int j = 0; j < 4; ++j) {
      float rg = sigm(aR[j]);
      float zg = sigm(aZ[j]);
      float ng = tanh_(aNI[j] + rg * aNH[j]);
      float hn = (1.0f - zg) * ng + zg * hold[j];
      hold[j] = hn;
      sH[cur ^ 1][row4 + j][m] = (h1)hn;
    }
    if (tid < 256) sX[cur ^ 1][tid >> 5][tid & 31] = (h1)xHold;
    bar_lds();  // the only barrier per step

    if (w >= 4) {
      f32x4 aE{bE, bE, bE, bE};
#pragma unroll
      for (int kt = 0; kt < 4; ++kt)
        aE = MFMA(afrag(&sH[cur ^ 1][0][0], 136, 32 * kt, lane),
                  swzfrag(sE, 16 * (w - 4), kt, lane), aE);
      if (lane < 32) {  // valid rows 0..7
#pragma unroll
        for (int j = 0; j < 4; ++j)
          ctx16[((size_t)t * BB + b0 + row4 + j) * CC + ccE] = (h1)aE[j];
      }
    }
    xHold = xFly;
  }
}

// ---------------- Kernel 2: z0 + SDE scan + projection (r9-proven) ----------
__global__ __launch_bounds__(512, 2) void k_sde(
    const float* __restrict__ ts, const float* __restrict__ eps0,
    const float* __restrict__ noise, const float* __restrict__ qz0W,
    const float* __restrict__ qz0b, const float* __restrict__ fW1,
    const float* __restrict__ fb1, const float* __restrict__ fW2,
    const float* __restrict__ fb2, const float* __restrict__ fW3,
    const float* __restrict__ fb3, const float* __restrict__ hW1,
    const float* __restrict__ hb1, const float* __restrict__ hW2,
    const float* __restrict__ hb2, const float* __restrict__ hW3,
    const float* __restrict__ hb3, const float* __restrict__ projW,
    const float* __restrict__ projb, const float* __restrict__ gtab,
    const h1* __restrict__ ctx16, float* __restrict__ out) {
  __shared__ alignas(16) h1 sC[16][72];
  __shared__ alignas(16) h1 sY16[16][40];
  __shared__ alignas(16) h1 sA1[16][136], sB1[16][136];
  __shared__ alignas(16) h1 sA2[16][136], sB2[16][136];
  __shared__ alignas(16) h1 sW3f[32 * 128], sW3h[32 * 128];
  __shared__ float sG[32][GROW];
  __shared__ float sDt[128], sSq[128];
  __shared__ float sTmp[16][33];

  const int tid = threadIdx.x;
  const int lane = tid & 63, w = tid >> 6;
  const int b0 = blockIdx.x * 16;
  const int coln = lane & 15, row4 = (lane >> 4) << 2;
  const bool isF = (w < 4);
  const int t2 = isF ? w : (w - 4);
  const int colA = 32 * t2 + coln, colB = colA + 16;

  f16x8 wL1a[3], wL1b[3], wL2a[4], wL2b[4], wPj;
  if (isF) {
#pragma unroll
    for (int kt = 0; kt < 3; ++kt) {
      wL1a[kt] = bfrag(fW1, 96, 32 * t2, 32 * kt, lane);
      wL1b[kt] = bfrag(fW1, 96, 32 * t2 + 16, 32 * kt, lane);
    }
#pragma unroll
    for (int kt = 0; kt < 4; ++kt) {
      wL2a[kt] = bfrag(fW2, HH, 32 * t2, 32 * kt, lane);
      wL2b[kt] = bfrag(fW2, HH, 32 * t2 + 16, 32 * kt, lane);
    }
  } else {
    wL1a[0] = bfrag(hW1, 32, 32 * t2, 0, lane);
    wL1b[0] = bfrag(hW1, 32, 32 * t2 + 16, 0, lane);
#pragma unroll
    for (int kt = 0; kt < 4; ++kt) {
      wL2a[kt] = bfrag(hW2, HH, 32 * t2, 32 * kt, lane);
      wL2b[kt] = bfrag(hW2, HH, 32 * t2 + 16, 32 * kt, lane);
    }
  }
  const float bL1a = isF ? fb1[colA] : hb1[colA];
  const float bL1b = isF ? fb1[colB] : hb1[colB];
  const float bL2a = isF ? fb2[colA] : hb2[colA];
  const float bL2b = isF ? fb2[colB] : hb2[colB];

  float bF3 = 0.f, bH3 = 0.f, bPj = 0.f;
  int cu = 0, ccp = 0, srow = 0, scol = 0;
  if (w == 4 || w == 5) {
    cu = 16 * (w - 4) + coln;
    bF3 = fb3[cu];
    bH3 = hb3[cu];
  } else if (w >= 6) {
    ccp = 16 * (w - 6) + coln;
    wPj = bfrag(projW, LL, 16 * (w - 6), 0, lane);
    bPj = projb[ccp];
    const int sidx = tid - 384;
    srow = sidx >> 3;
    scol = (sidx & 7) * 8;
  }

  store_swz(sW3f, fW3, 32, tid, 512);
  store_swz(sW3h, hW3, 32, tid, 512);
  for (int i = tid; i < 32 * GROW; i += 512) (&sG[0][0])[i] = gtab[i];
  if (tid < TT - 1) {
    float d = ts[tid + 1] - ts[tid];
    sDt[tid] = d;
    sSq[tid] = __fsqrt_rn(d);
  }
  *(h2*)&sC[tid >> 5][2 * (tid & 31)] =
      *(const h2*)(ctx16 + (size_t)(b0 + (tid >> 5)) * CC + 2 * (tid & 31));
  __syncthreads();

  {
    const int sr = tid >> 5, sc = tid & 31;
    float m0 = qz0b[sc], s0 = qz0b[32 + sc];
    const float* qm = qz0W + sc * 64;
    const float* qs = qz0W + (32 + sc) * 64;
#pragma unroll 4
    for (int k = 0; k < 64; ++k) {
      float cv = (float)sC[sr][k];
      m0 = fmaf(qm[k], cv, m0);
      s0 = fmaf(qs[k], cv, s0);
    }
    float z = fmaf(__expf(s0), eps0[(size_t)(b0 + sr) * LL + sc], m0);
    sTmp[sr][sc] = z;
    sY16[sr][sc] = (h1)z;
  }
  f16x8 cHold;
  if (w >= 6)
    cHold = *(const f16x8*)(ctx16 + ((size_t)1 * BB + b0 + srow) * CC + scol);
  float nHold[4] = {0.f, 0.f, 0.f, 0.f};
  if (w == 4 || w == 5) {
#pragma unroll
    for (int j = 0; j < 4; ++j)
      nHold[j] = noise[(size_t)(b0 + row4 + j) * LL + cu];
  }
  __syncthreads();

  float yreg[4] = {0.f, 0.f, 0.f, 0.f}, lq[4] = {0.f, 0.f, 0.f, 0.f};
  if (w == 4 || w == 5) {
#pragma unroll
    for (int j = 0; j < 4; ++j) yreg[j] = sTmp[row4 + j][cu];
  }

  f32x4 accA{bL1a, bL1a, bL1a, bL1a}, accB{bL1b, bL1b, bL1b, bL1b};
  if (isF) {
    f16x8 c0 = afrag(&sC[0][0], 72, 0, lane);
    f16x8 c1 = afrag(&sC[0][0], 72, 32, lane);
    accA = MFMA(c0, wL1a[1], accA);
    accA = MFMA(c1, wL1a[2], accA);
    accB = MFMA(c0, wL1b[1], accB);
    accB = MFMA(c1, wL1b[2], accB);
  }

  for (int t = 0; t < TT - 1; ++t) {
    f16x8 cFly;
    if (w >= 6) {
      const int tc = (t + 2 <= TT - 1) ? t + 2 : TT - 1;
      cFly = *(const f16x8*)(ctx16 + ((size_t)tc * BB + b0 + srow) * CC + scol);
    }
    float nFly[4];
    if (w == 4 || w == 5) {
      const int tn = (t + 1 < TT - 1) ? t + 1 : TT - 2;
#pragma unroll
      for (int j = 0; j < 4; ++j)
        nFly[j] = noise[((size_t)tn * BB + b0 + row4 + j) * LL + cu];
    }

    if (isF) {
#pragma unroll
      for (int kt = 0; kt < 3; ++kt) {
        PIN(wL1a[kt]);
        PIN(wL1b[kt]);
      }
    } else {
      PIN(wL1a[0]);
      PIN(wL1b[0]);
    }
#pragma unroll
    for (int kt = 0; kt < 4; ++kt) {
      PIN(wL2a[kt]);
      PIN(wL2b[kt]);
    }
    if (w >= 6) PIN(wPj);

    // ---- P1 ----
    f16x8 aY = afrag(&sY16[0][0], 40, 0, lane);
    if (isF) {
      accA = MFMA(aY, wL1a[0], accA);
      accB = MFMA(aY, wL1b[0], accB);
#pragma unroll
      for (int j = 0; j < 4; ++j) {
        sA1[row4 + j][colA] = (h1)splus(accA[j]);
        sA1[row4 + j][colB] = (h1)splus(accB[j]);
      }
    } else {
      f32x4 hA{bL1a, bL1a, bL1a, bL1a}, hB{bL1b, bL1b, bL1b, bL1b};
      hA = MFMA(aY, wL1a[0], hA);
      hB = MFMA(aY, wL1b[0], hB);
#pragma unroll
      for (int j = 0; j < 4; ++j) {
        sB1[row4 + j][colA] = (h1)splus(hA[j]);
        sB1[row4 + j][colB] = (h1)splus(hB[j]);
      }
    }
    bar_lds();  // BAR1

    // ---- P2 ----
    {
      const h1* src = isF ? &sA1[0][0] : &sB1[0][0];
      h1* dst = isF ? &sA2[0][0] : &sB2[0][0];
      f32x4 pA{bL2a, bL2a, bL2a, bL2a}, pB{bL2b, bL2b, bL2b, bL2b};
#pragma unroll
      for (int kt = 0; kt < 4; ++kt) {
        f16x8 a = afrag(src, 136, 32 * kt, lane);
        pA = MFMA(a, wL2a[kt], pA);
        pB = MFMA(a, wL2b[kt], pB);
      }
#pragma unroll
      for (int j = 0; j < 4; ++j) {
        dst[(size_t)(row4 + j) * 136 + colA] = (h1)splus(pA[j]);
        dst[(size_t)(row4 + j) * 136 + colB] = (h1)splus(pB[j]);
      }
    }
    if (w >= 6) {
      *(f16x8*)&sC[srow][scol] = cHold;
      cHold = cFly;
    }
    bar_lds();  // BAR2

    // ---- P3 ----
    if (isF) {
      f16x8 c0 = afrag(&sC[0][0], 72, 0, lane);
      f16x8 c1 = afrag(&sC[0][0], 72, 32, lane);
      accA = f32x4{bL1a, bL1a, bL1a, bL1a};
      accB = f32x4{bL1b, bL1b, bL1b, bL1b};
      accA = MFMA(c0, wL1a[1], accA);
      accA = MFMA(c1, wL1a[2], accA);
      accB = MFMA(c0, wL1b[1], accB);
      accB = MFMA(c1, wL1b[2], accB);
    } else if (w < 6) {
      f32x4 aF{bF3, bF3, bF3, bF3}, aH{bH3, bH3, bH3, bH3};
#pragma unroll
      for (int kt = 0; kt < 4; ++kt) {
        aF = MFMA(afrag(&sA2[0][0], 136, 32 * kt, lane),
                  swzfrag(sW3f, 16 * (w - 4), kt, lane), aF);
        aH = MFMA(afrag(&sB2[0][0], 136, 32 * kt, lane),
                  swzfrag(sW3h, 16 * (w - 4), kt, lane), aH);
      }
      const float dtv = sDt[t], sqdt = sSq[t];
      const float* g = sG[cu];
#pragma unroll
      for (int j = 0; j < 4; ++j) {
        float p = fminf(fmaxf(fmaf(yreg[j], 32.f / 3.f, 128.f), 0.f), 255.999f);
        const int i = (int)p;
        const float fr = p - (float)i;
        const float gv = fmaf(g[i + 1] - g[i], fr, g[i]);
        const float uv = (aF[j] - aH[j]) / gv;
        lq[j] = fmaf(0.5f * uv * uv, dtv, lq[j]);
        yreg[j] = fmaf(aF[j], dtv, yreg[j]) + gv * sqdt * nHold[j];
        sY16[row4 + j][cu] = (h1)yreg[j];
      }
#pragma unroll
      for (int j = 0; j < 4; ++j) nHold[j] = nFly[j];
    } else {
      f32x4 ap{bPj, bPj, bPj, bPj};
      ap = MFMA(aY, wPj, ap);
#pragma unroll
      for (int j = 0; j < 4; ++j)
        out[((size_t)t * BB + b0 + row4 + j) * DD + ccp] = ap[j];
    }
    bar_lds();  // BAR3
  }

  if (w >= 6) {
    f16x8 aYf = afrag(&sY16[0][0], 40, 0, lane);
    f32x4 ap{bPj, bPj, bPj, bPj};
    ap = MFMA(aYf, wPj, ap);
#pragma unroll
    for (int j = 0; j < 4; ++j)
      out[((size_t)(TT - 1) * BB + b0 + row4 + j) * DD + ccp] = ap[j];
  }
  if (w == 4 || w == 5) {
#pragma unroll
    for (int j = 0; j < 4; ++j) sTmp[row4 + j][cu] = lq[j];
  }
  __syncthreads();
  if (tid < 16) {
    float s = 0.f;
#pragma unroll
    for (int k = 0; k < 32; ++k) s += sTmp[tid][k];
    out[(size_t)TT * BB * DD + b0 + tid] = s;
  }
}

extern "C" void kernel_launch(void* const* d_in, const int* in_sizes, int n_in,
                              void* d_out, int out_size, void* d_ws,
                              size_t ws_size, hipStream_t stream) {
  const float* xs = (const float*)d_in[0];
  const float* ts = (const float*)d_in[1];
  const float* eps0 = (const float*)d_in[2];
  const float* noise = (const float*)d_in[3];
  const float* Wih = (const float*)d_in[4];
  const float* Whh = (const float*)d_in[5];
  const float* bih = (const float*)d_in[6];
  const float* bhh = (const float*)d_in[7];
  const float* encW = (const float*)d_in[8];
  const float* encb = (const float*)d_in[9];
  const float* qz0W = (const float*)d_in[10];
  const float* qz0b = (const float*)d_in[11];
  const float* fW1 = (const float*)d_in[12];
  const float* fb1 = (const float*)d_in[13];
  const float* fW2 = (const float*)d_in[14];
  const float* fb2 = (const float*)d_in[15];
  const float* fW3 = (const float*)d_in[16];
  const float* fb3 = (const float*)d_in[17];
  const float* hW1 = (const float*)d_in[18];
  const float* hb1 = (const float*)d_in[19];
  const float* hW2 = (const float*)d_in[20];
  const float* hb2 = (const float*)d_in[21];
  const float* hW3 = (const float*)d_in[22];
  const float* hb3 = (const float*)d_in[23];
  const float* gW1 = (const float*)d_in[24];
  const float* gb1 = (const float*)d_in[25];
  const float* gW2 = (const float*)d_in[26];
  const float* gb2 = (const float*)d_in[27];
  const float* projW = (const float*)d_in[28];
  const float* projb = (const float*)d_in[29];
  float* out = (float*)d_out;
  h1* ctx16 = (h1*)d_out;      // ctx[t,b,64] f16 aliases xs_hat[t,b,32] f32
  float* gtab = (float*)d_ws;  // 32*260*4 B

  k_gtab<<<32, 320, 0, stream>>>(gW1, gb1, gW2, gb2, gtab);
  k_gru<<<512, 512, 0, stream>>>(xs, Wih, Whh, bih, bhh, encW, encb, ctx16);
  k_sde<<<256, 512, 0, stream>>>(ts, eps0, noise, qz0W, qz0b, fW1, fb1, fW2,
                                 fb2, fW3, fb3, hW1, hb1, hW2, hb2, hW3, hb3,
                                 projW, projb, gtab, ctx16, out);
}

// Round 11
// 382.691 us; speedup vs baseline: 1.2398x; 1.2398x over previous
//
#include <hip/hip_runtime.h>

// RallyNet latent-SDE, round 11: FUSED kernel.
// One 256-block x 512-thread kernel; GRU runs 1 step ahead of the SDE in the
// same block. ctx lives only in LDS (double-buffered) - no global round-trip.
// Per step t: P1 = GRU gates(t+1) + SDE L1 | P2 = SDE L2 + encoder->ctx(t+1)
//             P3 = preP1(ctx t+1) + L3+update (w4-5) + projection (w6-7).
// 3 lgkm-only barriers/step (global prefetches/stores never drained).
// Weights: GRU Wih/Whh pinned (60 VGPR); SDE L1/L2 pinned per role; encW,
// fW3, hW3 in XOR-swizzled LDS. diag-g via PWL table built in d_ws.

#define TT 100
#define BB 4096
#define DD 32
#define LL 32
#define CC 64
#define HH 128
#define GROW 260

typedef _Float16 h1;
typedef _Float16 h2 __attribute__((ext_vector_type(2)));
typedef _Float16 f16x8 __attribute__((ext_vector_type(8)));
typedef float f32x4 __attribute__((ext_vector_type(4)));

#define MFMA(a, b, c) __builtin_amdgcn_mfma_f32_16x16x32_f16(a, b, c, 0, 0, 0)
#define PIN(x) asm volatile("" : "+v"(x))

// lgkmcnt-only barrier: orders LDS producer->consumer without draining vmcnt.
__device__ __forceinline__ void bar_lds() {
  __builtin_amdgcn_sched_barrier(0);
  asm volatile("s_waitcnt lgkmcnt(0)" ::: "memory");
  __builtin_amdgcn_s_barrier();
  asm volatile("" ::: "memory");
  __builtin_amdgcn_sched_barrier(0);
}

__device__ __forceinline__ float sigm(float x) {
  return 1.0f / (1.0f + __expf(-x));
}
__device__ __forceinline__ float tanh_(float x) {
  float e = __expf(2.0f * fminf(x, 15.0f));
  return (e - 1.0f) / (e + 1.0f);
}
__device__ __forceinline__ float splus(float x) {
  return __logf(1.0f + __expf(x));  // inputs bounded |x| << 80
}

__device__ __forceinline__ f16x8 bfrag(const float* __restrict__ W, int K,
                                       int n0, int k0, int lane) {
  const float* p = W + (size_t)(n0 + (lane & 15)) * K + k0 + ((lane >> 4) << 3);
  f16x8 r;
#pragma unroll
  for (int j = 0; j < 8; ++j) r[j] = (h1)p[j];
  return r;
}

__device__ __forceinline__ f16x8 afrag(const h1* base, int ld, int k0,
                                       int lane) {
  return *(const f16x8*)(base + (size_t)(lane & 15) * ld + k0 +
                         ((lane >> 4) << 3));
}

// swizzled f16 weight LDS (rows 256B; XOR bits 4-6 by row&7)
__device__ __forceinline__ void store_swz(h1* base, const float* __restrict__ W,
                                          int rows, int tid, int nthr) {
  for (int idx = tid; idx < rows * 64; idx += nthr) {
    const int n = idx >> 6, kp = idx & 63;
    float2 v = *(const float2*)(W + (size_t)n * HH + 2 * kp);
    h2 hv;
    hv[0] = (h1)v.x;
    hv[1] = (h1)v.y;
    int byte = n * 256 + kp * 4;
    byte ^= (n & 7) << 4;
    *(h2*)((char*)base + byte) = hv;
  }
}
__device__ __forceinline__ f16x8 swzfrag(const h1* base, int n0, int kt,
                                         int lane) {
  const int n = n0 + (lane & 15);
  int byte = n * 256 + kt * 64 + ((lane >> 4) << 4);
  byte ^= (n & 7) << 4;
  return *(const f16x8*)((const char*)base + byte);
}

// ---------------- g-table build ----------------
__global__ __launch_bounds__(320) void k_gtab(
    const float* __restrict__ gW1, const float* __restrict__ gb1,
    const float* __restrict__ gW2, const float* __restrict__ gb2,
    float* __restrict__ gtab) {
  const int l = blockIdx.x;
  const int e = threadIdx.x;
  if (e >= 257) return;
  const float yv = -12.f + (float)e * (24.f / 256.f);
  const float* w1 = gW1 + l * HH;
  const float* bb = gb1 + l * HH;
  const float* w2 = gW2 + l * HH;
  float a = 0.f;
#pragma unroll 4
  for (int h = 0; h < HH; ++h)
    a = fmaf(splus(fmaf(yv, w1[h], bb[h])), w2[h], a);
  gtab[l * GROW + e] = sigm(a + gb2[l]);
}

// ---------------- Fused GRU + encoder + SDE ----------------
__global__ __launch_bounds__(512, 2) void k_fused(
    const float* __restrict__ xs, const float* __restrict__ ts,
    const float* __restrict__ eps0, const float* __restrict__ noise,
    const float* __restrict__ Wih, const float* __restrict__ Whh,
    const float* __restrict__ bih, const float* __restrict__ bhh,
    const float* __restrict__ encW, const float* __restrict__ encb,
    const float* __restrict__ qz0W, const float* __restrict__ qz0b,
    const float* __restrict__ fW1, const float* __restrict__ fb1,
    const float* __restrict__ fW2, const float* __restrict__ fb2,
    const float* __restrict__ fW3, const float* __restrict__ fb3,
    const float* __restrict__ hW1, const float* __restrict__ hb1,
    const float* __restrict__ hW2, const float* __restrict__ hb2,
    const float* __restrict__ hW3, const float* __restrict__ hb3,
    const float* __restrict__ projW, const float* __restrict__ projb,
    const float* __restrict__ gtab, float* __restrict__ out) {
  __shared__ alignas(16) h1 sHb[2][16][136];
  __shared__ alignas(16) h1 sX[2][16][40];
  __shared__ alignas(16) h1 sE[64 * 128];  // swizzled encW
  __shared__ alignas(16) h1 sCtx[2][16][72];
  __shared__ alignas(16) h1 sY16[16][40];
  __shared__ alignas(16) h1 sA1[16][136], sB1[16][136];
  __shared__ alignas(16) h1 sA2[16][136], sB2[16][136];
  __shared__ alignas(16) h1 sW3f[32 * 128], sW3h[32 * 128];
  __shared__ float sG[32][GROW];
  __shared__ float sDt[128], sSq[128];
  __shared__ float sTmp[16][33];

  const int tid = threadIdx.x;
  const int lane = tid & 63, w = tid >> 6;
  const int b0 = blockIdx.x * 16;
  const int coln = lane & 15, row4 = (lane >> 4) << 2;

  // ---- GRU pinned weights + biases (all waves; wave owns units 16w..) ----
  f16x8 wIH[3], wHH[3][4];
#pragma unroll
  for (int g = 0; g < 3; ++g) {
    wIH[g] = bfrag(Wih, DD, 128 * g + 16 * w, 0, lane);
#pragma unroll
    for (int kt = 0; kt < 4; ++kt)
      wHH[g][kt] = bfrag(Whh, HH, 128 * g + 16 * w, 32 * kt, lane);
  }
  const int m = 16 * w + coln;
  const float b_r = bih[m] + bhh[m];
  const float b_z = bih[128 + m] + bhh[128 + m];
  const float b_ni = bih[256 + m];
  const float b_nh = bhh[256 + m];
  const int ccE = (w >= 4) ? 16 * (w - 4) + coln : 0;
  const float bE = (w >= 4) ? encb[ccE] : 0.f;

  // ---- SDE role weights: w0-3 f-path, w4-7 h-path (N=32/wave) ----
  const bool isF = (w < 4);
  const int t2 = isF ? w : (w - 4);
  const int colA = 32 * t2 + coln, colB = colA + 16;
  f16x8 wL1a[3], wL1b[3], wL2a[4], wL2b[4], wPj;
  if (isF) {
#pragma unroll
    for (int kt = 0; kt < 3; ++kt) {
      wL1a[kt] = bfrag(fW1, 96, 32 * t2, 32 * kt, lane);
      wL1b[kt] = bfrag(fW1, 96, 32 * t2 + 16, 32 * kt, lane);
    }
#pragma unroll
    for (int kt = 0; kt < 4; ++kt) {
      wL2a[kt] = bfrag(fW2, HH, 32 * t2, 32 * kt, lane);
      wL2b[kt] = bfrag(fW2, HH, 32 * t2 + 16, 32 * kt, lane);
    }
  } else {
    wL1a[0] = bfrag(hW1, 32, 32 * t2, 0, lane);
    wL1b[0] = bfrag(hW1, 32, 32 * t2 + 16, 0, lane);
#pragma unroll
    for (int kt = 0; kt < 4; ++kt) {
      wL2a[kt] = bfrag(hW2, HH, 32 * t2, 32 * kt, lane);
      wL2b[kt] = bfrag(hW2, HH, 32 * t2 + 16, 32 * kt, lane);
    }
  }
  const float bL1a = isF ? fb1[colA] : hb1[colA];
  const float bL1b = isF ? fb1[colB] : hb1[colB];
  const float bL2a = isF ? fb2[colA] : hb2[colA];
  const float bL2b = isF ? fb2[colB] : hb2[colB];

  float bF3 = 0.f, bH3 = 0.f, bPj = 0.f;
  int cu = 0, ccp = 0;
  if (w == 4 || w == 5) {
    cu = 16 * (w - 4) + coln;
    bF3 = fb3[cu];
    bH3 = hb3[cu];
  } else if (w >= 6) {
    ccp = 16 * (w - 6) + coln;
    wPj = bfrag(projW, LL, 16 * (w - 6), 0, lane);
    bPj = projb[ccp];
  }

  // ---- LDS constant staging ----
  store_swz(sE, encW, 64, tid, 512);
  store_swz(sW3f, fW3, 32, tid, 512);
  store_swz(sW3h, hW3, 32, tid, 512);
  for (int i = tid; i < 32 * GROW; i += 512) (&sG[0][0])[i] = gtab[i];
  if (tid < TT - 1) {
    float d = ts[tid + 1] - ts[tid];
    sDt[tid] = d;
    sSq[tid] = __fsqrt_rn(d);
  }
  for (int i = tid; i < 16 * 136; i += 512) (&sHb[0][0][0])[i] = (h1)0.0f;
  sX[0][tid >> 5][tid & 31] = (h1)xs[(size_t)b0 * DD + tid];
  float xHold = xs[(size_t)BB * DD + (size_t)b0 * DD + tid];  // x[1]
  float hold[4] = {0.f, 0.f, 0.f, 0.f};
  __syncthreads();

  // ---- prime: GRU step g=0 -> hs[0] -> ctx[0] ----
  {
    f16x8 ax = afrag(&sX[0][0][0], 40, 0, lane);
    f32x4 aR{b_r, b_r, b_r, b_r}, aZ{b_z, b_z, b_z, b_z};
    f32x4 aNI{b_ni, b_ni, b_ni, b_ni}, aNH{b_nh, b_nh, b_nh, b_nh};
    aR = MFMA(ax, wIH[0], aR);
    aZ = MFMA(ax, wIH[1], aZ);
    aNI = MFMA(ax, wIH[2], aNI);
#pragma unroll
    for (int kt = 0; kt < 4; ++kt) {
      f16x8 ah = afrag(&sHb[0][0][0], 136, 32 * kt, lane);
      aR = MFMA(ah, wHH[0][kt], aR);
      aZ = MFMA(ah, wHH[1][kt], aZ);
      aNH = MFMA(ah, wHH[2][kt], aNH);
    }
#pragma unroll
    for (int j = 0; j < 4; ++j) {
      float rg = sigm(aR[j]);
      float zg = sigm(aZ[j]);
      float ng = tanh_(aNI[j] + rg * aNH[j]);
      float hn = (1.0f - zg) * ng + zg * hold[j];
      hold[j] = hn;
      sHb[1][row4 + j][m] = (h1)hn;
    }
    sX[1][tid >> 5][tid & 31] = (h1)xHold;  // x[1] for g=1
    xHold = xs[(size_t)2 * BB * DD + (size_t)b0 * DD + tid];  // x[2]
  }
  bar_lds();
  if (w >= 4) {  // encoder g=0 -> sCtx[0]
    f32x4 aE{bE, bE, bE, bE};
#pragma unroll
    for (int kt = 0; kt < 4; ++kt)
      aE = MFMA(afrag(&sHb[1][0][0], 136, 32 * kt, lane),
                swzfrag(sE, 16 * (w - 4), kt, lane), aE);
#pragma unroll
    for (int j = 0; j < 4; ++j) sCtx[0][row4 + j][ccE] = (h1)aE[j];
  }
  bar_lds();

  // ---- z0 = mean + exp(logstd)*eps0 ----
  {
    const int sr = tid >> 5, sc = tid & 31;
    float m0 = qz0b[sc], s0 = qz0b[32 + sc];
    const float* qm = qz0W + sc * 64;
    const float* qs = qz0W + (32 + sc) * 64;
#pragma unroll 4
    for (int k = 0; k < 64; ++k) {
      float cv = (float)sCtx[0][sr][k];
      m0 = fmaf(qm[k], cv, m0);
      s0 = fmaf(qs[k], cv, s0);
    }
    float z = fmaf(__expf(s0), eps0[(size_t)(b0 + sr) * LL + sc], m0);
    sTmp[sr][sc] = z;
    sY16[sr][sc] = (h1)z;
  }
  __syncthreads();

  float yreg[4] = {0.f, 0.f, 0.f, 0.f}, lq[4] = {0.f, 0.f, 0.f, 0.f};
  float nHold[4] = {0.f, 0.f, 0.f, 0.f};
  if (w == 4 || w == 5) {
#pragma unroll
    for (int j = 0; j < 4; ++j) {
      yreg[j] = sTmp[row4 + j][cu];
      nHold[j] = noise[(size_t)(b0 + row4 + j) * LL + cu];
    }
  }

  // preP1 for t=0 (ctx part of SDE layer-1 f)
  f32x4 accA{bL1a, bL1a, bL1a, bL1a}, accB{bL1b, bL1b, bL1b, bL1b};
  if (isF) {
    f16x8 c0 = afrag(&sCtx[0][0][0], 72, 0, lane);
    f16x8 c1 = afrag(&sCtx[0][0][0], 72, 32, lane);
    accA = MFMA(c0, wL1a[1], accA);
    accA = MFMA(c1, wL1a[2], accA);
    accB = MFMA(c0, wL1b[1], accB);
    accB = MFMA(c1, wL1b[2], accB);
  }

  for (int t = 0; t < TT - 1; ++t) {
    const int cur = t & 1;
    // prefetch issues (fly across lgkm-only barriers)
    const int tf = (t + 3 < TT) ? (t + 3) : (TT - 1);
    const float xFly = xs[(size_t)tf * BB * DD + (size_t)b0 * DD + tid];
    float nFly[4];
    if (w == 4 || w == 5) {
      const int tn = (t + 1 < TT - 1) ? t + 1 : TT - 2;
#pragma unroll
      for (int j = 0; j < 4; ++j)
        nFly[j] = noise[((size_t)tn * BB + b0 + row4 + j) * LL + cu];
    }

#pragma unroll
    for (int g = 0; g < 3; ++g) {
      PIN(wIH[g]);
#pragma unroll
      for (int kt = 0; kt < 4; ++kt) PIN(wHH[g][kt]);
    }
    if (isF) {
#pragma unroll
      for (int kt = 0; kt < 3; ++kt) {
        PIN(wL1a[kt]);
        PIN(wL1b[kt]);
      }
    } else {
      PIN(wL1a[0]);
      PIN(wL1b[0]);
    }
#pragma unroll
    for (int kt = 0; kt < 4; ++kt) {
      PIN(wL2a[kt]);
      PIN(wL2b[kt]);
    }
    if (w >= 6) PIN(wPj);

    // ---- P1: GRU gates g=t+1 + SDE L1 ----
    f16x8 aY = afrag(&sY16[0][0], 40, 0, lane);
    {
      f16x8 ax = afrag(&sX[cur ^ 1][0][0], 40, 0, lane);
      f32x4 aR{b_r, b_r, b_r, b_r}, aZ{b_z, b_z, b_z, b_z};
      f32x4 aNI{b_ni, b_ni, b_ni, b_ni}, aNH{b_nh, b_nh, b_nh, b_nh};
      aR = MFMA(ax, wIH[0], aR);
      aZ = MFMA(ax, wIH[1], aZ);
      aNI = MFMA(ax, wIH[2], aNI);
#pragma unroll
      for (int kt = 0; kt < 4; ++kt) {
        f16x8 ah = afrag(&sHb[cur ^ 1][0][0], 136, 32 * kt, lane);
        aR = MFMA(ah, wHH[0][kt], aR);
        aZ = MFMA(ah, wHH[1][kt], aZ);
        aNH = MFMA(ah, wHH[2][kt], aNH);
      }
#pragma unroll
      for (int j = 0; j < 4; ++j) {
        float rg = sigm(aR[j]);
        float zg = sigm(aZ[j]);
        float ng = tanh_(aNI[j] + rg * aNH[j]);
        float hn = (1.0f - zg) * ng + zg * hold[j];
        hold[j] = hn;
        sHb[cur][row4 + j][m] = (h1)hn;
      }
    }
    if (isF) {
      accA = MFMA(aY, wL1a[0], accA);
      accB = MFMA(aY, wL1b[0], accB);
#pragma unroll
      for (int j = 0; j < 4; ++j) {
        sA1[row4 + j][colA] = (h1)splus(accA[j]);
        sA1[row4 + j][colB] = (h1)splus(accB[j]);
      }
    } else {
      f32x4 hA{bL1a, bL1a, bL1a, bL1a}, hB{bL1b, bL1b, bL1b, bL1b};
      hA = MFMA(aY, wL1a[0], hA);
      hB = MFMA(aY, wL1b[0], hB);
#pragma unroll
      for (int j = 0; j < 4; ++j) {
        sB1[row4 + j][colA] = (h1)splus(hA[j]);
        sB1[row4 + j][colB] = (h1)splus(hB[j]);
      }
    }
    sX[cur][tid >> 5][tid & 31] = (h1)xHold;  // x[t+2]
    bar_lds();  // BAR1

    // ---- P2: SDE L2 + encoder -> ctx[t+1] ----
    {
      const h1* src = isF ? &sA1[0][0] : &sB1[0][0];
      h1* dst = isF ? &sA2[0][0] : &sB2[0][0];
      f32x4 pA{bL2a, bL2a, bL2a, bL2a}, pB{bL2b, bL2b, bL2b, bL2b};
#pragma unroll
      for (int kt = 0; kt < 4; ++kt) {
        f16x8 a = afrag(src, 136, 32 * kt, lane);
        pA = MFMA(a, wL2a[kt], pA);
        pB = MFMA(a, wL2b[kt], pB);
      }
#pragma unroll
      for (int j = 0; j < 4; ++j) {
        dst[(size_t)(row4 + j) * 136 + colA] = (h1)splus(pA[j]);
        dst[(size_t)(row4 + j) * 136 + colB] = (h1)splus(pB[j]);
      }
    }
    if (w >= 4) {
      f32x4 aE{bE, bE, bE, bE};
#pragma unroll
      for (int kt = 0; kt < 4; ++kt)
        aE = MFMA(afrag(&sHb[cur][0][0], 136, 32 * kt, lane),
                  swzfrag(sE, 16 * (w - 4), kt, lane), aE);
#pragma unroll
      for (int j = 0; j < 4; ++j) sCtx[cur ^ 1][row4 + j][ccE] = (h1)aE[j];
    }
    bar_lds();  // BAR2

    // ---- P3: preP1 (f) | L3+update (w4-5) | projection (w6-7) ----
    if (isF) {
      f16x8 c0 = afrag(&sCtx[cur ^ 1][0][0], 72, 0, lane);
      f16x8 c1 = afrag(&sCtx[cur ^ 1][0][0], 72, 32, lane);
      accA = f32x4{bL1a, bL1a, bL1a, bL1a};
      accB = f32x4{bL1b, bL1b, bL1b, bL1b};
      accA = MFMA(c0, wL1a[1], accA);
      accA = MFMA(c1, wL1a[2], accA);
      accB = MFMA(c0, wL1b[1], accB);
      accB = MFMA(c1, wL1b[2], accB);
    } else if (w < 6) {
      f32x4 aF{bF3, bF3, bF3, bF3}, aH{bH3, bH3, bH3, bH3};
#pragma unroll
      for (int kt = 0; kt < 4; ++kt) {
        aF = MFMA(afrag(&sA2[0][0], 136, 32 * kt, lane),
                  swzfrag(sW3f, 16 * (w - 4), kt, lane), aF);
        aH = MFMA(afrag(&sB2[0][0], 136, 32 * kt, lane),
                  swzfrag(sW3h, 16 * (w - 4), kt, lane), aH);
      }
      const float dtv = sDt[t], sqdt = sSq[t];
      const float* g = sG[cu];
#pragma unroll
      for (int j = 0; j < 4; ++j) {
        float p = fminf(fmaxf(fmaf(yreg[j], 32.f / 3.f, 128.f), 0.f), 255.999f);
        const int i = (int)p;
        const float fr = p - (float)i;
        const float gv = fmaf(g[i + 1] - g[i], fr, g[i]);
        const float uv = (aF[j] - aH[j]) / gv;
        lq[j] = fmaf(0.5f * uv * uv, dtv, lq[j]);
        yreg[j] = fmaf(aF[j], dtv, yreg[j]) + gv * sqdt * nHold[j];
        sY16[row4 + j][cu] = (h1)yreg[j];
      }
#pragma unroll
      for (int j = 0; j < 4; ++j) nHold[j] = nFly[j];
    } else {
      f32x4 ap{bPj, bPj, bPj, bPj};
      ap = MFMA(aY, wPj, ap);
#pragma unroll
      for (int j = 0; j < 4; ++j)
        out[((size_t)t * BB + b0 + row4 + j) * DD + ccp] = ap[j];
    }
    bar_lds();  // BAR3
    xHold = xFly;
  }

  // final projection xs_hat[99] from y[99]
  if (w >= 6) {
    f16x8 aYf = afrag(&sY16[0][0], 40, 0, lane);
    f32x4 ap{bPj, bPj, bPj, bPj};
    ap = MFMA(aYf, wPj, ap);
#pragma unroll
    for (int j = 0; j < 4; ++j)
      out[((size_t)(TT - 1) * BB + b0 + row4 + j) * DD + ccp] = ap[j];
  }
  // logqp reduce
  if (w == 4 || w == 5) {
#pragma unroll
    for (int j = 0; j < 4; ++j) sTmp[row4 + j][cu] = lq[j];
  }
  __syncthreads();
  if (tid < 16) {
    float s = 0.f;
#pragma unroll
    for (int k = 0; k < 32; ++k) s += sTmp[tid][k];
    out[(size_t)TT * BB * DD + b0 + tid] = s;
  }
}

extern "C" void kernel_launch(void* const* d_in, const int* in_sizes, int n_in,
                              void* d_out, int out_size, void* d_ws,
                              size_t ws_size, hipStream_t stream) {
  const float* xs = (const float*)d_in[0];
  const float* ts = (const float*)d_in[1];
  const float* eps0 = (const float*)d_in[2];
  const float* noise = (const float*)d_in[3];
  const float* Wih = (const float*)d_in[4];
  const float* Whh = (const float*)d_in[5];
  const float* bih = (const float*)d_in[6];
  const float* bhh = (const float*)d_in[7];
  const float* encW = (const float*)d_in[8];
  const float* encb = (const float*)d_in[9];
  const float* qz0W = (const float*)d_in[10];
  const float* qz0b = (const float*)d_in[11];
  const float* fW1 = (const float*)d_in[12];
  const float* fb1 = (const float*)d_in[13];
  const float* fW2 = (const float*)d_in[14];
  const float* fb2 = (const float*)d_in[15];
  const float* fW3 = (const float*)d_in[16];
  const float* fb3 = (const float*)d_in[17];
  const float* hW1 = (const float*)d_in[18];
  const float* hb1 = (const float*)d_in[19];
  const float* hW2 = (const float*)d_in[20];
  const float* hb2 = (const float*)d_in[21];
  const float* hW3 = (const float*)d_in[22];
  const float* hb3 = (const float*)d_in[23];
  const float* gW1 = (const float*)d_in[24];
  const float* gb1 = (const float*)d_in[25];
  const float* gW2 = (const float*)d_in[26];
  const float* gb2 = (const float*)d_in[27];
  const float* projW = (const float*)d_in[28];
  const float* projb = (const float*)d_in[29];
  float* out = (float*)d_out;
  float* gtab = (float*)d_ws;  // 32*260*4 B

  k_gtab<<<32, 320, 0, stream>>>(gW1, gb1, gW2, gb2, gtab);
  k_fused<<<256, 512, 0, stream>>>(xs, ts, eps0, noise, Wih, Whh, bih, bhh,
                                   encW, encb, qz0W, qz0b, fW1, fb1, fW2, fb2,
                                   fW3, fb3, hW1, hb1, hW2, hb2, hW3, hb3,
                                   projW, projb, gtab, out);
}

// Round 12
// 342.231 us; speedup vs baseline: 1.3864x; 1.1182x over previous
//
#include <hip/hip_runtime.h>

// RallyNet latent-SDE, round 12 = r9 base (best: 347us) + two cuts:
//  (1) static weights in REGISTERS on their consumer waves (fW3/hW3 on k_sde
//      w4-5, encW on k_gru w4-7) - removes post-barrier LDS weight-read
//      latency from the critical waves; LDS shrinks (58KB / 11KB).
//  (2) v_rcp-based division for sigm/tanh/update (was IEEE v_div ~10 ops,
//      on the dependent gate chain).
// Structure unchanged: k_gru 256x512 (16 rows/block), 1 lgkm-only barrier;
// k_sde 256x512, 8 waves, N=32/wave, preP1 ctx-hoist, depth-2 prefetch,
// 3 lgkm-only barriers; diag-g PWL table in d_ws; ctx f16 aliases d_out.

#define TT 100
#define BB 4096
#define DD 32
#define LL 32
#define CC 64
#define HH 128
#define GROW 260

typedef _Float16 h1;
typedef _Float16 h2 __attribute__((ext_vector_type(2)));
typedef _Float16 f16x8 __attribute__((ext_vector_type(8)));
typedef float f32x4 __attribute__((ext_vector_type(4)));

#define MFMA(a, b, c) __builtin_amdgcn_mfma_f32_16x16x32_f16(a, b, c, 0, 0, 0)
#define PIN(x) asm volatile("" : "+v"(x))

// lgkmcnt-only barrier: orders LDS producer->consumer without draining vmcnt
__device__ __forceinline__ void bar_lds() {
  __builtin_amdgcn_sched_barrier(0);
  asm volatile("s_waitcnt lgkmcnt(0)" ::: "memory");
  __builtin_amdgcn_s_barrier();
  asm volatile("" ::: "memory");
  __builtin_amdgcn_sched_barrier(0);
}

__device__ __forceinline__ float sigm(float x) {
  return __frcp_rn(1.0f + __expf(-x));
}
__device__ __forceinline__ float tanh_(float x) {
  float e = __expf(2.0f * fminf(x, 15.0f));
  return (e - 1.0f) * __frcp_rn(e + 1.0f);
}
__device__ __forceinline__ float splus(float x) {
  return __logf(1.0f + __expf(x));  // inputs bounded |x| << 80
}

// B-fragment of row-major W[N][K] tile (n0,k0)
__device__ __forceinline__ f16x8 bfrag(const float* __restrict__ W, int K,
                                       int n0, int k0, int lane) {
  const float* p = W + (size_t)(n0 + (lane & 15)) * K + k0 + ((lane >> 4) << 3);
  f16x8 r;
#pragma unroll
  for (int j = 0; j < 8; ++j) r[j] = (h1)p[j];
  return r;
}

// A-fragment from LDS row-major tile
__device__ __forceinline__ f16x8 afrag(const h1* base, int ld, int k0,
                                       int lane) {
  return *(const f16x8*)(base + (size_t)(lane & 15) * ld + k0 +
                         ((lane >> 4) << 3));
}

// ---------------- g-table build ----------------
__global__ __launch_bounds__(320) void k_gtab(
    const float* __restrict__ gW1, const float* __restrict__ gb1,
    const float* __restrict__ gW2, const float* __restrict__ gb2,
    float* __restrict__ gtab) {
  const int l = blockIdx.x;
  const int e = threadIdx.x;
  if (e >= 257) return;
  const float yv = -12.f + (float)e * (24.f / 256.f);
  const float* w1 = gW1 + l * HH;
  const float* bb = gb1 + l * HH;
  const float* w2 = gW2 + l * HH;
  float a = 0.f;
#pragma unroll 4
  for (int h = 0; h < HH; ++h)
    a = fmaf(splus(fmaf(yv, w1[h], bb[h])), w2[h], a);
  gtab[l * GROW + e] = sigm(a + gb2[l]);
}

// ---------------- Kernel 1: GRU + encoder ----------------
__global__ __launch_bounds__(512, 2) void k_gru(
    const float* __restrict__ xs, const float* __restrict__ Wih,
    const float* __restrict__ Whh, const float* __restrict__ bih,
    const float* __restrict__ bhh, const float* __restrict__ encW,
    const float* __restrict__ encb, h1* __restrict__ ctx16) {
  __shared__ alignas(16) h1 sH[2][16][136];
  __shared__ alignas(16) h1 sX[2][16][40];

  const int tid = threadIdx.x;
  const int lane = tid & 63, w = tid >> 6;
  const int b0 = blockIdx.x * 16;
  const int coln = lane & 15, row4 = (lane >> 4) << 2;

  f16x8 wIH[3], wHH[3][4], wE[4];
#pragma unroll
  for (int g = 0; g < 3; ++g) {
    wIH[g] = bfrag(Wih, DD, 128 * g + 16 * w, 0, lane);
#pragma unroll
    for (int kt = 0; kt < 4; ++kt)
      wHH[g][kt] = bfrag(Whh, HH, 128 * g + 16 * w, 32 * kt, lane);
  }
  const int m = 16 * w + coln;
  const float b_r = bih[m] + bhh[m];
  const float b_z = bih[128 + m] + bhh[128 + m];
  const float b_ni = bih[256 + m];
  const float b_nh = bhh[256 + m];
  const int ccE = (w >= 4) ? 16 * (w - 4) + coln : 0;
  const float bE = (w >= 4) ? encb[ccE] : 0.f;
  if (w >= 4) {
#pragma unroll
    for (int kt = 0; kt < 4; ++kt)
      wE[kt] = bfrag(encW, HH, 16 * (w - 4), 32 * kt, lane);
  }

  for (int i = tid; i < 16 * 136; i += 512) (&sH[0][0][0])[i] = (h1)0.0f;
  sX[0][tid >> 5][tid & 31] = (h1)xs[(size_t)b0 * DD + tid];
  float xHold = xs[(size_t)1 * BB * DD + (size_t)b0 * DD + tid];
  float hold[4] = {0.f, 0.f, 0.f, 0.f};
  __syncthreads();

  for (int t = 0; t < TT; ++t) {
    const int cur = t & 1;
    const int tf = (t + 2 < TT) ? (t + 2) : (TT - 1);
    const float xFly = xs[(size_t)tf * BB * DD + (size_t)b0 * DD + tid];

#pragma unroll
    for (int g = 0; g < 3; ++g) {
      PIN(wIH[g]);
#pragma unroll
      for (int kt = 0; kt < 4; ++kt) PIN(wHH[g][kt]);
    }
    if (w >= 4) {
#pragma unroll
      for (int kt = 0; kt < 4; ++kt) PIN(wE[kt]);
    }

    f16x8 ax = afrag(&sX[cur][0][0], 40, 0, lane);
    f32x4 aR{b_r, b_r, b_r, b_r}, aZ{b_z, b_z, b_z, b_z};
    f32x4 aNI{b_ni, b_ni, b_ni, b_ni}, aNH{b_nh, b_nh, b_nh, b_nh};
    aR = MFMA(ax, wIH[0], aR);
    aZ = MFMA(ax, wIH[1], aZ);
    aNI = MFMA(ax, wIH[2], aNI);
#pragma unroll
    for (int kt = 0; kt < 4; ++kt) {
      f16x8 ah = afrag(&sH[cur][0][0], 136, 32 * kt, lane);
      aR = MFMA(ah, wHH[0][kt], aR);
      aZ = MFMA(ah, wHH[1][kt], aZ);
      aNH = MFMA(ah, wHH[2][kt], aNH);
    }
#pragma unroll
    for (int j = 0; j < 4; ++j) {
      float rg = sigm(aR[j]);
      float zg = sigm(aZ[j]);
      float ng = tanh_(aNI[j] + rg * aNH[j]);
      float hn = (1.0f - zg) * ng + zg * hold[j];
      hold[j] = hn;
      sH[cur ^ 1][row4 + j][m] = (h1)hn;
    }
    sX[cur ^ 1][tid >> 5][tid & 31] = (h1)xHold;
    bar_lds();  // the only barrier per step

    if (w >= 4) {
      f32x4 aE{bE, bE, bE, bE};
#pragma unroll
      for (int kt = 0; kt < 4; ++kt)
        aE = MFMA(afrag(&sH[cur ^ 1][0][0], 136, 32 * kt, lane), wE[kt], aE);
#pragma unroll
      for (int j = 0; j < 4; ++j)
        ctx16[((size_t)t * BB + b0 + row4 + j) * CC + ccE] = (h1)aE[j];
    }
    xHold = xFly;
  }
}

// ---------------- Kernel 2: z0 + SDE scan + projection ----------------
__global__ __launch_bounds__(512, 2) void k_sde(
    const float* __restrict__ ts, const float* __restrict__ eps0,
    const float* __restrict__ noise, const float* __restrict__ qz0W,
    const float* __restrict__ qz0b, const float* __restrict__ fW1,
    const float* __restrict__ fb1, const float* __restrict__ fW2,
    const float* __restrict__ fb2, const float* __restrict__ fW3,
    const float* __restrict__ fb3, const float* __restrict__ hW1,
    const float* __restrict__ hb1, const float* __restrict__ hW2,
    const float* __restrict__ hb2, const float* __restrict__ hW3,
    const float* __restrict__ hb3, const float* __restrict__ projW,
    const float* __restrict__ projb, const float* __restrict__ gtab,
    const h1* __restrict__ ctx16, float* __restrict__ out) {
  __shared__ alignas(16) h1 sC[16][72];
  __shared__ alignas(16) h1 sY16[16][40];
  __shared__ alignas(16) h1 sA1[16][136], sB1[16][136];
  __shared__ alignas(16) h1 sA2[16][136], sB2[16][136];
  __shared__ float sG[32][GROW];
  __shared__ float sDt[128], sSq[128];
  __shared__ float sTmp[16][33];

  const int tid = threadIdx.x;
  const int lane = tid & 63, w = tid >> 6;
  const int b0 = blockIdx.x * 16;
  const int coln = lane & 15, row4 = (lane >> 4) << 2;
  const bool isF = (w < 4);
  const int t2 = isF ? w : (w - 4);
  const int colA = 32 * t2 + coln, colB = colA + 16;

  f16x8 wL1a[3], wL1b[3], wL2a[4], wL2b[4], wF3[4], wH3[4], wPj;
  if (isF) {
#pragma unroll
    for (int kt = 0; kt < 3; ++kt) {
      wL1a[kt] = bfrag(fW1, 96, 32 * t2, 32 * kt, lane);
      wL1b[kt] = bfrag(fW1, 96, 32 * t2 + 16, 32 * kt, lane);
    }
#pragma unroll
    for (int kt = 0; kt < 4; ++kt) {
      wL2a[kt] = bfrag(fW2, HH, 32 * t2, 32 * kt, lane);
      wL2b[kt] = bfrag(fW2, HH, 32 * t2 + 16, 32 * kt, lane);
    }
  } else {
    wL1a[0] = bfrag(hW1, 32, 32 * t2, 0, lane);
    wL1b[0] = bfrag(hW1, 32, 32 * t2 + 16, 0, lane);
#pragma unroll
    for (int kt = 0; kt < 4; ++kt) {
      wL2a[kt] = bfrag(hW2, HH, 32 * t2, 32 * kt, lane);
      wL2b[kt] = bfrag(hW2, HH, 32 * t2 + 16, 32 * kt, lane);
    }
  }
  const float bL1a = isF ? fb1[colA] : hb1[colA];
  const float bL1b = isF ? fb1[colB] : hb1[colB];
  const float bL2a = isF ? fb2[colA] : hb2[colA];
  const float bL2b = isF ? fb2[colB] : hb2[colB];

  float bF3 = 0.f, bH3 = 0.f, bPj = 0.f;
  int cu = 0, ccp = 0, srow = 0, scol = 0;
  if (w == 4 || w == 5) {
    cu = 16 * (w - 4) + coln;
    bF3 = fb3[cu];
    bH3 = hb3[cu];
#pragma unroll
    for (int kt = 0; kt < 4; ++kt) {
      wF3[kt] = bfrag(fW3, HH, 16 * (w - 4), 32 * kt, lane);
      wH3[kt] = bfrag(hW3, HH, 16 * (w - 4), 32 * kt, lane);
    }
  } else if (w >= 6) {
    ccp = 16 * (w - 6) + coln;
    wPj = bfrag(projW, LL, 16 * (w - 6), 0, lane);
    bPj = projb[ccp];
    const int sidx = tid - 384;
    srow = sidx >> 3;
    scol = (sidx & 7) * 8;
  }

  for (int i = tid; i < 32 * GROW; i += 512) (&sG[0][0])[i] = gtab[i];
  if (tid < TT - 1) {
    float d = ts[tid + 1] - ts[tid];
    sDt[tid] = d;
    sSq[tid] = __fsqrt_rn(d);
  }
  *(h2*)&sC[tid >> 5][2 * (tid & 31)] =
      *(const h2*)(ctx16 + (size_t)(b0 + (tid >> 5)) * CC + 2 * (tid & 31));
  __syncthreads();

  {
    const int sr = tid >> 5, sc = tid & 31;
    float m0 = qz0b[sc], s0 = qz0b[32 + sc];
    const float* qm = qz0W + sc * 64;
    const float* qs = qz0W + (32 + sc) * 64;
#pragma unroll 4
    for (int k = 0; k < 64; ++k) {
      float cv = (float)sC[sr][k];
      m0 = fmaf(qm[k], cv, m0);
      s0 = fmaf(qs[k], cv, s0);
    }
    float z = fmaf(__expf(s0), eps0[(size_t)(b0 + sr) * LL + sc], m0);
    sTmp[sr][sc] = z;
    sY16[sr][sc] = (h1)z;
  }
  f16x8 cHold;
  if (w >= 6)
    cHold = *(const f16x8*)(ctx16 + ((size_t)1 * BB + b0 + srow) * CC + scol);
  float nHold[4] = {0.f, 0.f, 0.f, 0.f};
  if (w == 4 || w == 5) {
#pragma unroll
    for (int j = 0; j < 4; ++j)
      nHold[j] = noise[(size_t)(b0 + row4 + j) * LL + cu];
  }
  __syncthreads();

  float yreg[4] = {0.f, 0.f, 0.f, 0.f}, lq[4] = {0.f, 0.f, 0.f, 0.f};
  if (w == 4 || w == 5) {
#pragma unroll
    for (int j = 0; j < 4; ++j) yreg[j] = sTmp[row4 + j][cu];
  }

  f32x4 accA{bL1a, bL1a, bL1a, bL1a}, accB{bL1b, bL1b, bL1b, bL1b};
  if (isF) {
    f16x8 c0 = afrag(&sC[0][0], 72, 0, lane);
    f16x8 c1 = afrag(&sC[0][0], 72, 32, lane);
    accA = MFMA(c0, wL1a[1], accA);
    accA = MFMA(c1, wL1a[2], accA);
    accB = MFMA(c0, wL1b[1], accB);
    accB = MFMA(c1, wL1b[2], accB);
  }

  for (int t = 0; t < TT - 1; ++t) {
    f16x8 cFly;
    if (w >= 6) {
      const int tc = (t + 2 <= TT - 1) ? t + 2 : TT - 1;
      cFly = *(const f16x8*)(ctx16 + ((size_t)tc * BB + b0 + srow) * CC + scol);
    }
    float nFly[4];
    if (w == 4 || w == 5) {
      const int tn = (t + 1 < TT - 1) ? t + 1 : TT - 2;
#pragma unroll
      for (int j = 0; j < 4; ++j)
        nFly[j] = noise[((size_t)tn * BB + b0 + row4 + j) * LL + cu];
    }

    if (isF) {
#pragma unroll
      for (int kt = 0; kt < 3; ++kt) {
        PIN(wL1a[kt]);
        PIN(wL1b[kt]);
      }
    } else {
      PIN(wL1a[0]);
      PIN(wL1b[0]);
    }
#pragma unroll
    for (int kt = 0; kt < 4; ++kt) {
      PIN(wL2a[kt]);
      PIN(wL2b[kt]);
    }
    if (w == 4 || w == 5) {
#pragma unroll
      for (int kt = 0; kt < 4; ++kt) {
        PIN(wF3[kt]);
        PIN(wH3[kt]);
      }
    } else if (w >= 6) {
      PIN(wPj);
    }

    // ---- P1 ----
    f16x8 aY = afrag(&sY16[0][0], 40, 0, lane);
    if (isF) {
      accA = MFMA(aY, wL1a[0], accA);
      accB = MFMA(aY, wL1b[0], accB);
#pragma unroll
      for (int j = 0; j < 4; ++j) {
        sA1[row4 + j][colA] = (h1)splus(accA[j]);
        sA1[row4 + j][colB] = (h1)splus(accB[j]);
      }
    } else {
      f32x4 hA{bL1a, bL1a, bL1a, bL1a}, hB{bL1b, bL1b, bL1b, bL1b};
      hA = MFMA(aY, wL1a[0], hA);
      hB = MFMA(aY, wL1b[0], hB);
#pragma unroll
      for (int j = 0; j < 4; ++j) {
        sB1[row4 + j][colA] = (h1)splus(hA[j]);
        sB1[row4 + j][colB] = (h1)splus(hB[j]);
      }
    }
    bar_lds();  // BAR1

    // ---- P2 ----
    {
      const h1* src = isF ? &sA1[0][0] : &sB1[0][0];
      h1* dst = isF ? &sA2[0][0] : &sB2[0][0];
      f32x4 pA{bL2a, bL2a, bL2a, bL2a}, pB{bL2b, bL2b, bL2b, bL2b};
#pragma unroll
      for (int kt = 0; kt < 4; ++kt) {
        f16x8 a = afrag(src, 136, 32 * kt, lane);
        pA = MFMA(a, wL2a[kt], pA);
        pB = MFMA(a, wL2b[kt], pB);
      }
#pragma unroll
      for (int j = 0; j < 4; ++j) {
        dst[(size_t)(row4 + j) * 136 + colA] = (h1)splus(pA[j]);
        dst[(size_t)(row4 + j) * 136 + colB] = (h1)splus(pB[j]);
      }
    }
    if (w >= 6) {
      *(f16x8*)&sC[srow][scol] = cHold;
      cHold = cFly;
    }
    bar_lds();  // BAR2

    // ---- P3 ----
    if (isF) {
      f16x8 c0 = afrag(&sC[0][0], 72, 0, lane);
      f16x8 c1 = afrag(&sC[0][0], 72, 32, lane);
      accA = f32x4{bL1a, bL1a, bL1a, bL1a};
      accB = f32x4{bL1b, bL1b, bL1b, bL1b};
      accA = MFMA(c0, wL1a[1], accA);
      accA = MFMA(c1, wL1a[2], accA);
      accB = MFMA(c0, wL1b[1], accB);
      accB = MFMA(c1, wL1b[2], accB);
    } else if (w < 6) {
      f32x4 aF{bF3, bF3, bF3, bF3}, aH{bH3, bH3, bH3, bH3};
#pragma unroll
      for (int kt = 0; kt < 4; ++kt) {
        aF = MFMA(afrag(&sA2[0][0], 136, 32 * kt, lane), wF3[kt], aF);
        aH = MFMA(afrag(&sB2[0][0], 136, 32 * kt, lane), wH3[kt], aH);
      }
      const float dtv = sDt[t], sqdt = sSq[t];
      const float* g = sG[cu];
#pragma unroll
      for (int j = 0; j < 4; ++j) {
        float p = fminf(fmaxf(fmaf(yreg[j], 32.f / 3.f, 128.f), 0.f), 255.999f);
        const int i = (int)p;
        const float fr = p - (float)i;
        const float gv = fmaf(g[i + 1] - g[i], fr, g[i]);
        const float uv = (aF[j] - aH[j]) * __frcp_rn(gv);
        lq[j] = fmaf(0.5f * uv * uv, dtv, lq[j]);
        yreg[j] = fmaf(aF[j], dtv, yreg[j]) + gv * sqdt * nHold[j];
        sY16[row4 + j][cu] = (h1)yreg[j];
      }
#pragma unroll
      for (int j = 0; j < 4; ++j) nHold[j] = nFly[j];
    } else {
      f32x4 ap{bPj, bPj, bPj, bPj};
      ap = MFMA(aY, wPj, ap);
#pragma unroll
      for (int j = 0; j < 4; ++j)
        out[((size_t)t * BB + b0 + row4 + j) * DD + ccp] = ap[j];
    }
    bar_lds();  // BAR3
  }

  if (w >= 6) {
    f16x8 aYf = afrag(&sY16[0][0], 40, 0, lane);
    f32x4 ap{bPj, bPj, bPj, bPj};
    ap = MFMA(aYf, wPj, ap);
#pragma unroll
    for (int j = 0; j < 4; ++j)
      out[((size_t)(TT - 1) * BB + b0 + row4 + j) * DD + ccp] = ap[j];
  }
  if (w == 4 || w == 5) {
#pragma unroll
    for (int j = 0; j < 4; ++j) sTmp[row4 + j][cu] = lq[j];
  }
  __syncthreads();
  if (tid < 16) {
    float s = 0.f;
#pragma unroll
    for (int k = 0; k < 32; ++k) s += sTmp[tid][k];
    out[(size_t)TT * BB * DD + b0 + tid] = s;
  }
}

extern "C" void kernel_launch(void* const* d_in, const int* in_sizes, int n_in,
                              void* d_out, int out_size, void* d_ws,
                              size_t ws_size, hipStream_t stream) {
  const float* xs = (const float*)d_in[0];
  const float* ts = (const float*)d_in[1];
  const float* eps0 = (const float*)d_in[2];
  const float* noise = (const float*)d_in[3];
  const float* Wih = (const float*)d_in[4];
  const float* Whh = (const float*)d_in[5];
  const float* bih = (const float*)d_in[6];
  const float* bhh = (const float*)d_in[7];
  const float* encW = (const float*)d_in[8];
  const float* encb = (const float*)d_in[9];
  const float* qz0W = (const float*)d_in[10];
  const float* qz0b = (const float*)d_in[11];
  const float* fW1 = (const float*)d_in[12];
  const float* fb1 = (const float*)d_in[13];
  const float* fW2 = (const float*)d_in[14];
  const float* fb2 = (const float*)d_in[15];
  const float* fW3 = (const float*)d_in[16];
  const float* fb3 = (const float*)d_in[17];
  const float* hW1 = (const float*)d_in[18];
  const float* hb1 = (const float*)d_in[19];
  const float* hW2 = (const float*)d_in[20];
  const float* hb2 = (const float*)d_in[21];
  const float* hW3 = (const float*)d_in[22];
  const float* hb3 = (const float*)d_in[23];
  const float* gW1 = (const float*)d_in[24];
  const float* gb1 = (const float*)d_in[25];
  const float* gW2 = (const float*)d_in[26];
  const float* gb2 = (const float*)d_in[27];
  const float* projW = (const float*)d_in[28];
  const float* projb = (const float*)d_in[29];
  float* out = (float*)d_out;
  h1* ctx16 = (h1*)d_out;      // ctx[t,b,64] f16 aliases xs_hat[t,b,32] f32
  float* gtab = (float*)d_ws;  // 32*260*4 B

  k_gtab<<<32, 320, 0, stream>>>(gW1, gb1, gW2, gb2, gtab);
  k_gru<<<256, 512, 0, stream>>>(xs, Wih, Whh, bih, bhh, encW, encb, ctx16);
  k_sde<<<256, 512, 0, stream>>>(ts, eps0, noise, qz0W, qz0b, fW1, fb1, fW2,
                                 fb2, fW3, fb3, hW1, hb1, hW2, hb2, hW3, hb3,
                                 projW, projb, gtab, ctx16, out);
}